// Round 2
// baseline (72.043 us; speedup 1.0000x reference)
//
#include <hip/hip_runtime.h>

// Grouped conv: x (1,48,56,56) f32, w (24,96,7) f32, groups=2.
// y[o,h,wo] = sum_{i<24,k<7} x[24g+i, h, wo+k-3] * w[i, o%96, k], pad 3 on W, g=o/96
// out[o,h,:] = y[o, (h - shift) mod 56, :]   (jnp.roll along H)
//
// Block = (group, oc-quad, h-tile of 8 rows), 256 threads = 4 waves.
// Wave w computes oc = ocq*4 + w. x tile (24ch x 8 rolled rows, zero-padded W)
// staged once in LDS and reused by all 4 waves. Weights are wave-uniform ->
// scalar loads. Lane (r,s): row r, outputs [7s, 7s+7).

#define H   56
#define W   56
#define CG  24
#define KW  7
#define HW_ (H * W)
#define STR 68   // LDS row stride in floats (<=2-way bank aliasing; 16B-aligned)
#define COFF 4   // data column offset inside LDS row (left zero pad)

__global__ __launch_bounds__(256) void conv7_roll_kernel(
    const float* __restrict__ x,
    const float* __restrict__ w,
    const int* __restrict__ shift_p,
    float* __restrict__ out)
{
    const int g     = blockIdx.x;   // 0..1
    const int ocq   = blockIdx.y;   // 0..23
    const int htile = blockIdx.z;   // 0..6
    const int tid   = threadIdx.x;  // 0..255

    __shared__ float xs[CG * 8 * STR];   // 52.2 KB

    const int shift = shift_p[0];
    const int h0    = htile * 8;

    // ---- stage x: 24 ch x 8 rows x 56 cols as float4, roll applied per row ----
    const float* xg = x + g * CG * HW_;
    for (int t = tid; t < CG * 8 * 14; t += 256) {
        const int ch = t / 112;
        const int rq = t - ch * 112;
        const int r  = rq / 14;
        const int q  = rq - r * 14;
        int hi = (h0 + r - shift) % H; if (hi < 0) hi += H;
        const float4 v = *(const float4*)(xg + ch * HW_ + hi * W + q * 4);
        *(float4*)(&xs[(ch * 8 + r) * STR + COFF + q * 4]) = v;
    }
    // zero pads: cols [0,4) and [60,68) of each of the 192 rows
    for (int t = tid; t < CG * 8 * 3; t += 256) {
        const int row   = t / 3;
        const int which = t - row * 3;
        const int col   = (which == 0) ? 0 : (which == 1 ? 60 : 64);
        *(float4*)(&xs[row * STR + col]) = make_float4(0.f, 0.f, 0.f, 0.f);
    }
    __syncthreads();

    // ---- compute ----
    const int wv   = tid >> 6;
    const int lane = tid & 63;
    const int r    = lane >> 3;     // 0..7 row in tile
    const int s    = lane & 7;      // 0..7 strip of 7 cols
    const int oc   = __builtin_amdgcn_readfirstlane(ocq * 4 + wv);
    const float* wp = w + oc * KW;  // w[i, oc, k] at wp[i*672 + k]

    float acc[7] = {0.f, 0.f, 0.f, 0.f, 0.f, 0.f, 0.f};

    // tap j (p = 7s-3+j) lives at LDS col COFF + 7s - 3 + j = 7s + 1 + j
    const float* xrow = &xs[r * STR + 7 * s + 1];

    #pragma unroll 4
    for (int i = 0; i < CG; ++i) {
        const float* xr = xrow + i * (8 * STR);
        float xv[13];
        #pragma unroll
        for (int j = 0; j < 13; ++j) xv[j] = xr[j];
        #pragma unroll
        for (int k = 0; k < KW; ++k) {
            const float wk = wp[i * (96 * KW) + k];
            #pragma unroll
            for (int j = 0; j < 7; ++j)
                acc[j] += xv[j + k] * wk;
        }
    }

    const int h_out = h0 + r;
    float* op = out + (g * 96 + oc) * HW_ + h_out * W + 7 * s;
    #pragma unroll
    for (int j = 0; j < 7; ++j)
        op[j] = acc[j];
}

extern "C" void kernel_launch(void* const* d_in, const int* in_sizes, int n_in,
                              void* d_out, int out_size, void* d_ws, size_t ws_size,
                              hipStream_t stream)
{
    const float* x     = (const float*)d_in[0];
    const float* w     = (const float*)d_in[1];
    const int*   shift = (const int*)d_in[2];
    float*       out   = (float*)d_out;

    dim3 grid(2, 24, 7);
    conv7_roll_kernel<<<grid, 256, 0, stream>>>(x, w, shift, out);
}